// Round 4
// baseline (332.393 us; speedup 1.0000x reference)
//
#include <hip/hip_runtime.h>
#include <hip/hip_bf16.h>

// Problem constants (B,C,T,H,W = 2,128,4,32,32; L=6; N=T*H*W=4096)
#define BCNT 2
#define CCH  128
#define NTOK 4096
#define NLAY 6
#define INV_SQRT 0.015625f   // 1/sqrt(4096)
#define LDP 136              // padded LDS cols (qkv kernel only)

using f32x4  = __attribute__((ext_vector_type(4))) float;
using bf16x8 = __attribute__((ext_vector_type(8))) short;

static __device__ __forceinline__ ushort f2bf(float f) {
  unsigned u = __float_as_uint(f);
  u += 0x7FFF + ((u >> 16) & 1);   // RNE
  return (ushort)(u >> 16);
}
// v_cvt_pk_bf16_f32: lo -> bits[15:0], hi -> bits[31:16] (T12 recipe)
static __device__ __forceinline__ uint pk2(float lo, float hi) {
  uint r;
  asm volatile("v_cvt_pk_bf16_f32 %0, %1, %2" : "=v"(r) : "v"(lo), "v"(hi));
  return r;
}
// async 16B/lane global->LDS DMA (LDS dest = wave-uniform base + lane*16)
static __device__ __forceinline__ void dma16(const void* g, void* l) {
  __builtin_amdgcn_global_load_lds(
      (const __attribute__((address_space(1))) unsigned int*)g,
      (__attribute__((address_space(3))) unsigned int*)l, 16, 0, 0);
}

// Stage a 128x128 bf16 tile (global row stride = gstride ushorts) into lds[128][LDP].
static __device__ __forceinline__ void stage_bf16(ushort (*lds)[LDP],
                                                  const ushort* __restrict__ g,
                                                  int gstride, int t) {
  #pragma unroll
  for (int p = 0; p < 8; ++p) {
    int idx = p * 256 + t;
    int row = idx >> 4, ch = (idx & 15) * 8;
    *(uint4*)&lds[row][ch] = *(const uint4*)(g + (size_t)row * gstride + ch);
  }
}

// Stage a 128x128 f32 tile (row stride 128) into lds bf16 [128][LDP].
static __device__ __forceinline__ void stage_f32(ushort (*lds)[LDP],
                                                 const float* __restrict__ g, int t) {
  #pragma unroll
  for (int p = 0; p < 16; ++p) {
    int idx = p * 256 + t;
    int row = idx >> 5, c4 = (idx & 31) * 4;
    float4 w = *(const float4*)(g + row * 128 + c4);
    lds[row][c4 + 0] = f2bf(w.x); lds[row][c4 + 1] = f2bf(w.y);
    lds[row][c4 + 2] = f2bf(w.z); lds[row][c4 + 3] = f2bf(w.w);
  }
}

// ---------------------------------------------------------------------------
// x f32 [B][C][N] -> xT bf16 [B][N][C]
// ---------------------------------------------------------------------------
__global__ __launch_bounds__(256) void transpose_kernel(
    const float* __restrict__ x, ushort* __restrict__ xT)
{
  __shared__ ushort ls[64][68];
  const int t = threadIdx.x;
  const int ntile = blockIdx.x * 64, ctile = blockIdx.y * 64, b = blockIdx.z;
  const float* xb = x + ((size_t)b * CCH + ctile) * NTOK + ntile;
  #pragma unroll
  for (int p = 0; p < 4; ++p) {
    int idx = p * 256 + t;
    int cc = idx >> 4, n4 = (idx & 15) * 4;
    float4 v = *(const float4*)(xb + (size_t)cc * NTOK + n4);
    ls[cc][n4 + 0] = f2bf(v.x); ls[cc][n4 + 1] = f2bf(v.y);
    ls[cc][n4 + 2] = f2bf(v.z); ls[cc][n4 + 3] = f2bf(v.w);
  }
  __syncthreads();
  ushort* ob = xT + ((size_t)b * NTOK + ntile) * CCH + ctile;
  #pragma unroll
  for (int p = 0; p < 16; ++p) {
    int idx = p * 256 + t;
    int nn = idx >> 6, cc = idx & 63;
    ob[(size_t)nn * CCH + cc] = ls[cc][nn];
  }
}

// ---------------------------------------------------------------------------
// qkv via MFMA. which=0: qT[n][o], 1: kT[n][o] (A=xT tile, B=W), 2: v[o][n]
// (A=W, B=xT tile). blockIdx.z = lidx*B + b, layer = l0+lidx.
// ---------------------------------------------------------------------------
__global__ __launch_bounds__(256) void qkv_kernel(
    const ushort* __restrict__ xT,
    const float* __restrict__ W1, const float* __restrict__ b1,
    const float* __restrict__ W2, const float* __restrict__ b2,
    const float* __restrict__ Wg, const float* __restrict__ bg,
    ushort* __restrict__ qT, ushort* __restrict__ kT, ushort* __restrict__ vb,
    int l0)
{
  __shared__ ushort as[128][LDP];
  __shared__ ushort bs[128][LDP];
  const int t = threadIdx.x;
  const int ntile = blockIdx.x * 128;
  const int which = blockIdx.y;
  const int z = blockIdx.z;
  const int b = z & 1, lidx = z >> 1, layer = l0 + lidx;
  const float* W; const float* bias; ushort* out;
  if (which == 0)      { W = W1; bias = b1; out = qT; }
  else if (which == 1) { W = W2; bias = b2; out = kT; }
  else                 { W = Wg; bias = bg; out = vb; }
  W += (size_t)layer * CCH * CCH; bias += (size_t)layer * CCH;
  const ushort* xb = xT + ((size_t)b * NTOK + ntile) * CCH;
  ushort* oz = out + (size_t)z * NTOK * CCH;

  if (which < 2) { stage_bf16(as, xb, CCH, t); stage_f32(bs, W, t); }
  else           { stage_f32(as, W, t);        stage_bf16(bs, xb, CCH, t); }
  __syncthreads();

  const int lane = t & 63, wave = t >> 6;
  const int l16 = lane & 15, lg = lane >> 4;
  const int wr = (wave >> 1) * 64, wc = (wave & 1) * 64;

  f32x4 acc[4][4];
  #pragma unroll
  for (int i = 0; i < 4; ++i)
    #pragma unroll
    for (int j = 0; j < 4; ++j) acc[i][j] = (f32x4)0.f;

  #pragma unroll
  for (int kk = 0; kk < 4; ++kk) {
    bf16x8 a[4], bb[4];
    #pragma unroll
    for (int i = 0; i < 4; ++i)
      a[i] = *(const bf16x8*)&as[wr + i * 16 + l16][kk * 32 + lg * 8];
    #pragma unroll
    for (int j = 0; j < 4; ++j)
      bb[j] = *(const bf16x8*)&bs[wc + j * 16 + l16][kk * 32 + lg * 8];
    #pragma unroll
    for (int i = 0; i < 4; ++i)
      #pragma unroll
      for (int j = 0; j < 4; ++j)
        acc[i][j] = __builtin_amdgcn_mfma_f32_16x16x32_bf16(a[i], bb[j], acc[i][j], 0, 0, 0);
  }

  if (which < 2) {   // out[n][o], bias along col o
    #pragma unroll
    for (int j = 0; j < 4; ++j) {
      float bv = bias[wc + j * 16 + l16];
      #pragma unroll
      for (int i = 0; i < 4; ++i)
        #pragma unroll
        for (int r = 0; r < 4; ++r) {
          int n = ntile + wr + i * 16 + lg * 4 + r;
          oz[(size_t)n * CCH + wc + j * 16 + l16] = f2bf(acc[i][j][r] + bv);
        }
    }
  } else {           // v[o][n], bias along row o
    #pragma unroll
    for (int i = 0; i < 4; ++i)
      #pragma unroll
      for (int r = 0; r < 4; ++r) {
        int o = wr + i * 16 + lg * 4 + r;
        float bv = bias[o];
        #pragma unroll
        for (int j = 0; j < 4; ++j)
          oz[(size_t)o * NTOK + ntile + wc + j * 16 + l16] = f2bf(acc[i][j][r] + bv);
      }
  }
}

// ---------------------------------------------------------------------------
// dcol: D[z][m] += sum_n exp(S[n][m]*scale). 1D grid (XCD-swizzled),
// gload_lds-staged XOR-swizzled 128x128 q/k tiles, 64 MFMA per wave.
// ---------------------------------------------------------------------------
__global__ __launch_bounds__(256, 2) void dcol_kernel(
    const ushort* __restrict__ qT, const ushort* __restrict__ kT,
    float* __restrict__ D)
{
  __shared__ ushort qs[128][128];
  __shared__ ushort ks[128][128];
  const int t = threadIdx.x;
  const int lane = t & 63, wave = t >> 6;
  const int l16 = lane & 15, lg = lane >> 4;

  const int bid = blockIdx.x, nblk = gridDim.x;
  const int wg = (bid & 7) * (nblk >> 3) + (bid >> 3);   // XCD swizzle
  const int z = wg >> 10, rem = wg & 1023;
  const int ntile = (rem & 31) * 128, mtile = (rem >> 5) * 128;

  const ushort* qz = qT + ((size_t)z * NTOK + ntile) * CCH;
  const ushort* kz = kT + ((size_t)z * NTOK + mtile) * CCH;

  #pragma unroll
  for (int j = 0; j < 8; ++j) {
    int row = wave * 32 + j * 4 + (lane >> 4);
    int src = ((lane & 15) ^ (row & 15)) * 8;
    dma16(qz + (size_t)row * CCH + src, &qs[wave * 32 + j * 4][0]);
    dma16(kz + (size_t)row * CCH + src, &ks[wave * 32 + j * 4][0]);
  }
  asm volatile("s_waitcnt vmcnt(0)" ::: "memory");
  __syncthreads();

  const int wr = (wave >> 1) * 64, wc = (wave & 1) * 64;
  f32x4 acc[4][4];
  #pragma unroll
  for (int i = 0; i < 4; ++i)
    #pragma unroll
    for (int j = 0; j < 4; ++j) acc[i][j] = (f32x4)0.f;

  #pragma unroll
  for (int kk = 0; kk < 4; ++kk) {
    bf16x8 a[4], bb[4];
    #pragma unroll
    for (int i = 0; i < 4; ++i)
      a[i] = *(const bf16x8*)&qs[wr + i * 16 + l16][((kk * 4 + lg) ^ l16) * 8];
    #pragma unroll
    for (int j = 0; j < 4; ++j)
      bb[j] = *(const bf16x8*)&ks[wc + j * 16 + l16][((kk * 4 + lg) ^ l16) * 8];
    #pragma unroll
    for (int i = 0; i < 4; ++i)
      #pragma unroll
      for (int j = 0; j < 4; ++j)
        acc[i][j] = __builtin_amdgcn_mfma_f32_16x16x32_bf16(a[i], bb[j], acc[i][j], 0, 0, 0);
  }

  float* Dz = D + (size_t)z * NTOK;
  #pragma unroll
  for (int j = 0; j < 4; ++j) {
    float cs = 0.f;
    #pragma unroll
    for (int i = 0; i < 4; ++i)
      #pragma unroll
      for (int r = 0; r < 4; ++r)
        cs += __expf(acc[i][j][r] * INV_SQRT);
    cs += __shfl_xor(cs, 16);
    cs += __shfl_xor(cs, 32);
    if (lg == 0) atomicAdd(&Dz[mtile + wc + j * 16 + l16], cs);
  }
}

// ---------------------------------------------------------------------------
// scalev: v[z][c][m] *= 1/(D[z][m]*L)  (bf16 in-place, 8 elems/thread)
// ---------------------------------------------------------------------------
__global__ __launch_bounds__(256) void scalev_kernel(
    ushort* __restrict__ vv, const float* __restrict__ D)
{
  size_t i8 = ((size_t)blockIdx.x * 256 + threadIdx.x) * 8;
  int m = (int)(i8 & (NTOK - 1));
  int z = (int)(i8 >> 19);               // per-z elems = C*N = 2^19
  const float* dp = D + (size_t)z * NTOK + m;
  uint4 u = *(uint4*)(vv + i8);
  float4 d0 = *(const float4*)dp;
  float4 d1 = *(const float4*)(dp + 4);
  uint w[4] = {u.x, u.y, u.z, u.w};
  float ds[8] = {d0.x, d0.y, d0.z, d0.w, d1.x, d1.y, d1.z, d1.w};
  #pragma unroll
  for (int d = 0; d < 4; ++d) {
    float r0 = __builtin_amdgcn_rcpf(ds[2 * d] * (float)NLAY);
    float r1 = __builtin_amdgcn_rcpf(ds[2 * d + 1] * (float)NLAY);
    float lo = __uint_as_float(w[d] << 16) * r0;
    float hi = __uint_as_float(w[d] & 0xFFFF0000u) * r1;
    w[d] = pk2(lo, hi);
  }
  *(uint4*)(vv + i8) = make_uint4(w[0], w[1], w[2], w[3]);
}

// ---------------------------------------------------------------------------
// pv: acc[b][n][c] += sum_m exp(S[n][m]*scale) * v'[c][m]   (v' = v/(D*L))
// 128-thread blocks, 2 waves x 64 n-rows. 32-m subtiles, K/V double-buffered
// via global_load_lds (pre-swizzled source). Swapped S^T -> in-register E
// A-frag build (cvt_pk + 8 shfl + 4 sel per 32m per 16n). LDS 32KB ->
// 4 blocks/CU at <=256 VGPR. Grid 1D XCD-swizzled: z*128 blocks.
// ---------------------------------------------------------------------------
__global__ __launch_bounds__(128, 2) void pv_kernel(
    const ushort* __restrict__ qT, const ushort* __restrict__ kT,
    const ushort* __restrict__ vv, float* __restrict__ accG)
{
  __shared__ ushort ks[2][32][128];   // [buf][m][c]
  __shared__ ushort vs[2][128][32];   // [buf][c][m]
  const int t = threadIdx.x;
  const int lane = t & 63, wave = t >> 6;
  const int l16 = lane & 15, lg = lane >> 4;

  const int bid = blockIdx.x, nblk = gridDim.x;
  const int wg = (bid & 7) * (nblk >> 3) + (bid >> 3);   // XCD swizzle
  const int z = wg >> 7, rem = wg & 127;
  const int ntile = (rem & 31) * 128;
  const int mstart = (rem >> 5) * 1024;                  // 32 subtiles of 32 m
  const int b = z & 1;

  const ushort* qz = qT + (size_t)z * NTOK * CCH;
  const ushort* kz = kT + (size_t)z * NTOK * CCH;
  const ushort* vz = vv + (size_t)z * NTOK * CCH;
  const int nw = wave * 64;

  // Q fragments (B-operand), 64 rows per wave, held for the whole block
  bf16x8 qf[4][4];
  #pragma unroll
  for (int i = 0; i < 4; ++i)
    #pragma unroll
    for (int kk = 0; kk < 4; ++kk)
      qf[i][kk] = *(const bf16x8*)(qz + (size_t)(ntile + nw + i * 16 + l16) * CCH
                                   + kk * 32 + lg * 8);

  f32x4 oacc[4][8];
  #pragma unroll
  for (int i = 0; i < 4; ++i)
    #pragma unroll
    for (int cf = 0; cf < 8; ++cf) oacc[i][cf] = (f32x4)0.f;

#define STAGE(p, msub) do {                                                   \
    _Pragma("unroll")                                                         \
    for (int j_ = 0; j_ < 4; ++j_) {                                          \
      int krow_ = wave * 16 + j_ * 4 + (lane >> 4);                           \
      dma16(kz + (size_t)((msub) + krow_) * CCH + (((lane & 15) ^ (krow_ & 15)) * 8), \
            &ks[p][wave * 16 + j_ * 4][0]);                                   \
      int vrow_ = wave * 64 + j_ * 16 + (lane >> 2);                          \
      dma16(vz + (size_t)vrow_ * NTOK + (msub) + (((lane & 3) ^ (vrow_ & 3)) * 8), \
            &vs[p][wave * 64 + j_ * 16][0]);                                  \
    }                                                                         \
  } while (0)

  int cur = 0;
  STAGE(0, mstart);
  asm volatile("s_waitcnt vmcnt(0)" ::: "memory");
  __builtin_amdgcn_s_barrier();

  for (int st = 0; st < 32; ++st) {
    if (st < 31) STAGE(cur ^ 1, mstart + (st + 1) * 32);

    // ---- S^T phase: lane holds S[n = nw+i*16+l16][m = mf*16+lg*4+r]
    f32x4 sacc[2][4];
    #pragma unroll
    for (int mf = 0; mf < 2; ++mf)
      #pragma unroll
      for (int i = 0; i < 4; ++i) sacc[mf][i] = (f32x4)0.f;
    __builtin_amdgcn_s_setprio(1);
    #pragma unroll
    for (int kk = 0; kk < 4; ++kk) {
      bf16x8 kf0 = *(const bf16x8*)&ks[cur][l16]     [((kk * 4 + lg) ^ l16) * 8];
      bf16x8 kf1 = *(const bf16x8*)&ks[cur][16 + l16][((kk * 4 + lg) ^ l16) * 8];
      #pragma unroll
      for (int i = 0; i < 4; ++i) {
        sacc[0][i] = __builtin_amdgcn_mfma_f32_16x16x32_bf16(kf0, qf[i][kk], sacc[0][i], 0, 0, 0);
        sacc[1][i] = __builtin_amdgcn_mfma_f32_16x16x32_bf16(kf1, qf[i][kk], sacc[1][i], 0, 0, 0);
      }
    }
    __builtin_amdgcn_s_setprio(0);

    // ---- exp + pack + redistribute -> E A-frags (per 16-n frame)
    bf16x8 ef[4];
    #pragma unroll
    for (int i = 0; i < 4; ++i) {
      uint wA0 = pk2(__expf(sacc[0][i][0] * INV_SQRT), __expf(sacc[0][i][1] * INV_SQRT));
      uint wA1 = pk2(__expf(sacc[0][i][2] * INV_SQRT), __expf(sacc[0][i][3] * INV_SQRT));
      uint wB0 = pk2(__expf(sacc[1][i][0] * INV_SQRT), __expf(sacc[1][i][1] * INV_SQRT));
      uint wB1 = pk2(__expf(sacc[1][i][2] * INV_SQRT), __expf(sacc[1][i][3] * INV_SQRT));
      int s  = l16 + ((lg & 1) << 5);
      int s2 = s + 16;
      uint a0 = (uint)__shfl((int)wA0, s),  b0 = (uint)__shfl((int)wB0, s);
      uint a1 = (uint)__shfl((int)wA1, s),  b1_ = (uint)__shfl((int)wB1, s);
      uint a2 = (uint)__shfl((int)wA0, s2), b2_ = (uint)__shfl((int)wB0, s2);
      uint a3 = (uint)__shfl((int)wA1, s2), b3 = (uint)__shfl((int)wB1, s2);
      bool loT = (lg < 2);
      int4 ei = make_int4((int)(loT ? a0 : b0), (int)(loT ? a1 : b1_),
                          (int)(loT ? a2 : b2_), (int)(loT ? a3 : b3));
      ef[i] = *(bf16x8*)&ei;
    }

    // ---- PV phase: V fragment per ch (transient), 4 MFMA each
    __builtin_amdgcn_s_setprio(1);
    #pragma unroll
    for (int ch = 0; ch < 8; ++ch) {
      bf16x8 vf = *(const bf16x8*)&vs[cur][ch * 16 + l16][(lg ^ (l16 & 3)) * 8];
      #pragma unroll
      for (int i = 0; i < 4; ++i)
        oacc[i][ch] = __builtin_amdgcn_mfma_f32_16x16x32_bf16(ef[i], vf, oacc[i][ch], 0, 0, 0);
    }
    __builtin_amdgcn_s_setprio(0);

    asm volatile("s_waitcnt vmcnt(0)" ::: "memory");
    __builtin_amdgcn_s_barrier();
    cur ^= 1;
  }
#undef STAGE

  float* az = accG + ((size_t)b * NTOK + ntile) * CCH;
  #pragma unroll
  for (int i = 0; i < 4; ++i)
    #pragma unroll
    for (int cf = 0; cf < 8; ++cf)
      #pragma unroll
      for (int r = 0; r < 4; ++r)
        atomicAdd(&az[(size_t)(nw + i * 16 + lg * 4 + r) * CCH + cf * 16 + l16],
                  oacc[i][cf][r]);
}

// ---------------------------------------------------------------------------
// out[b][c][n] = acc[b][n][c] + x[b][c][n]
// ---------------------------------------------------------------------------
__global__ __launch_bounds__(256) void finalize_kernel(
    const float* __restrict__ acc, const float* __restrict__ x,
    float* __restrict__ out)
{
  __shared__ float ts[64][65];
  const int t = threadIdx.x;
  const int ntile = blockIdx.x * 64, ctile = blockIdx.y * 64, b = blockIdx.z;
  const float* ab = acc + ((size_t)b * NTOK + ntile) * CCH + ctile;
  #pragma unroll
  for (int p = 0; p < 4; ++p) {
    int idx = p * 256 + t;
    int nn = idx >> 4, c4 = (idx & 15) * 4;
    float4 v = *(const float4*)(ab + (size_t)nn * CCH + c4);
    ts[nn][c4 + 0] = v.x; ts[nn][c4 + 1] = v.y;
    ts[nn][c4 + 2] = v.z; ts[nn][c4 + 3] = v.w;
  }
  __syncthreads();
  const size_t base = ((size_t)b * CCH + ctile) * NTOK + ntile;
  #pragma unroll
  for (int p = 0; p < 16; ++p) {
    int idx = p * 256 + t;
    int nn = idx & 63, cc = idx >> 6;
    size_t o = base + (size_t)cc * NTOK + nn;
    out[o] = ts[nn][cc] + x[o];
  }
}

// ---------------------------------------------------------------------------
extern "C" void kernel_launch(void* const* d_in, const int* in_sizes, int n_in,
                              void* d_out, int out_size, void* d_ws, size_t ws_size,
                              hipStream_t stream)
{
  const float* x  = (const float*)d_in[0];
  const float* W1 = (const float*)d_in[1];
  const float* b1 = (const float*)d_in[2];
  const float* W2 = (const float*)d_in[3];
  const float* b2 = (const float*)d_in[4];
  const float* Wg = (const float*)d_in[5];
  const float* bg = (const float*)d_in[6];
  float* out = (float*)d_out;

  const size_t PL = (size_t)BCNT * NTOK * CCH;   // 1,048,576 elements per slab
  const size_t DSZ = (size_t)BCNT * NTOK;        // 8192

  size_t need6 = PL * 2 + 3 * 6 * PL * 2 + 6 * DSZ * 4 + PL * 4;
  int nb = (ws_size >= need6) ? 6 : 1;

  char* p = (char*)d_ws;
  ushort* xT = (ushort*)p; p += PL * 2;
  ushort* qT = (ushort*)p; p += (size_t)nb * PL * 2;
  ushort* kT = (ushort*)p; p += (size_t)nb * PL * 2;
  ushort* vv = (ushort*)p; p += (size_t)nb * PL * 2;
  float*  D  = (float*)p;  p += (size_t)nb * DSZ * 4;
  float*  acc= (float*)p;  p += PL * 4;

  hipMemsetAsync(acc, 0, PL * 4, stream);
  transpose_kernel<<<dim3(NTOK / 64, CCH / 64, BCNT), 256, 0, stream>>>(x, xT);

  for (int l0 = 0; l0 < NLAY; l0 += nb) {
    const int LB = nb * BCNT;
    hipMemsetAsync(D, 0, (size_t)LB * NTOK * 4, stream);
    qkv_kernel<<<dim3(NTOK / 128, 3, LB), 256, 0, stream>>>(
        xT, W1, b1, W2, b2, Wg, bg, qT, kT, vv, l0);
    dcol_kernel<<<dim3(LB * 1024), 256, 0, stream>>>(qT, kT, D);
    scalev_kernel<<<dim3(LB * 256), 256, 0, stream>>>(vv, D);
    pv_kernel<<<dim3(LB * 128), 128, 0, stream>>>(qT, kT, vv, acc);
  }
  finalize_kernel<<<dim3(NTOK / 64, CCH / 64, BCNT), 256, 0, stream>>>(acc, x, out);
}